// Round 9
// baseline (879.680 us; speedup 1.0000x reference)
//
#include <hip/hip_runtime.h>
#include <hip/hip_bf16.h>

typedef __bf16 bf16;
typedef __bf16 bf16x4 __attribute__((ext_vector_type(4)));
typedef __bf16 bf16x8 __attribute__((ext_vector_type(8)));
typedef float  f32x4  __attribute__((ext_vector_type(4)));

#define EDIM 1536
#define DDIM 128
#define CDIM 1664   // E + D
#define TM   64
#define NCHA 48     // phase A chunks (32 k each)
#define NCHT 52     // + 4 phase B chunks

#define MFMA_B16(a, b, c) __builtin_amdgcn_mfma_f32_16x16x32_bf16((a), (b), (c), 0, 0, 0)

__device__ __forceinline__ float sigf(float x) { return 1.0f / (1.0f + __expf(-x)); }
__device__ __forceinline__ float tanhf_fast(float x) { return 2.0f / (1.0f + __expf(-2.0f * x)) - 1.0f; }

// f32 -> bf16 weight conversion into workspace
__global__ __launch_bounds__(256) void prep_convert(const float* __restrict__ w_ih,
                                                    const float* __restrict__ w_hh,
                                                    bf16* __restrict__ wib,
                                                    bf16* __restrict__ whb) {
  const int i = (blockIdx.x * 256 + threadIdx.x) * 4;
  const int TIH = 3 * DDIM * EDIM;
  const int THH = 3 * DDIM * DDIM;
  if (i < TIH) {
    const float4 v = *(const float4*)(w_ih + i);
    bf16x4 o = {(bf16)v.x, (bf16)v.y, (bf16)v.z, (bf16)v.w};
    *(bf16x4*)(wib + i) = o;
  } else if (i < TIH + THH) {
    const int j = i - TIH;
    const float4 v = *(const float4*)(w_hh + j);
    bf16x4 o = {(bf16)v.x, (bf16)v.y, (bf16)v.z, (bf16)v.w};
    *(bf16x4*)(whb + j) = o;
  }
}

// 256 thr = 4 waves; TM=64. Wave wn (0..3) owns gate-cols [32*wn,+32), ALL 64
// rows (mt 0..3). acc = 128 AGPR; launch_bounds(256,2) -> 256 regs, 2 blk/CU.
// W reg-staged into 80B-padded LDS (no XOR, 2-way reads), single-buffered,
// 2 barriers/chunk, W loads 1 chunk ahead (L2), emb loads 2 chunks ahead.
__global__ __launch_bounds__(256, 2) void gru_fused(
    const float* __restrict__ emb, const int* __restrict__ ids,
    const float* __restrict__ mem,
    const float* __restrict__ b_ih, const float* __restrict__ b_hh,
    const float* __restrict__ cls_w, const float* __restrict__ cls_b,
    const bf16* __restrict__ wib, const bf16* __restrict__ whb,
    float* __restrict__ logits, float* __restrict__ omem, int Nrows)
{
  __shared__ char  sW[30720];     // W chunk: 384 rows x 80B (64B data + 16B pad)
  __shared__ char  sA[2][5120];   // A slice dbuf: 64 rows x 80B
  __shared__ char  sPC[16384];    // phase B: prev gathered, 64 x 256B (proven swizzle)
  __shared__ float sLp[64][2];
  __shared__ int   sIds[64];

  const int t    = threadIdx.x;
  const int lane = t & 63;
  const int wn   = t >> 6;        // wave = gate-col group 0..3
  const int l15  = lane & 15;
  const int lq   = lane >> 4;     // 0..3
  const int m0   = blockIdx.x * TM;

  if (t < 64)  sIds[t] = (m0 + t < Nrows) ? ids[m0 + t] : 0;
  if (t < 128) sLp[t >> 1][t & 1] = cls_b[t & 1];

  // accumulators: 4 sets x [mt=4][sub=2] f32x4 = 128 AGPR
  f32x4 accR[4][2], accZ[4][2], accN[4][2], accH[4][2];
#pragma unroll
  for (int sub = 0; sub < 2; ++sub) {
    const int nc = wn * 32 + sub * 16 + l15;
    const float br = b_ih[nc] + b_hh[nc];
    const float bz = b_ih[128 + nc] + b_hh[128 + nc];
    const float bn = b_ih[256 + nc];
    const float bh = b_hh[256 + nc];
#pragma unroll
    for (int mt = 0; mt < 4; ++mt) {
      accR[mt][sub] = (f32x4){br, br, br, br};
      accZ[mt][sub] = (f32x4){bz, bz, bz, bz};
      accN[mt][sub] = (f32x4){bn, bn, bn, bn};
      accH[mt][sub] = (f32x4){bh, bh, bh, bh};
    }
  }

  // A staging: thread t owns row arow = t>>2, 8-f32 segment aseg = t&3
  const int  arow = t >> 2;
  const int  aseg = t & 3;
  const bool av   = (m0 + arow) < Nrows;
  const float* pA = emb + (size_t)(m0 + arow) * EDIM + aseg * 8;
  const int  awofs = arow * 80 + aseg * 16;
  const int  nb    = wn * 32 + l15;   // W read row base
  float lp0 = 0.f, lp1 = 0.f;

  uint4  wreg[6];
  const float4 fz = make_float4(0.f, 0.f, 0.f, 0.f);
  float4 aE0 = fz, aE1 = fz, aO0 = fz, aO1 = fz;

  // W chunk load (1536 segs / 256 thr = 6 each; 4 consecutive thr = 64B line)
#define LOADW(CI) do {                                                         \
    const int ci_ = (CI);                                                      \
    const bf16* bse_; int lda_, k0_;                                           \
    if (ci_ < NCHA) { bse_ = wib; lda_ = EDIM; k0_ = ci_ * 32; }               \
    else            { bse_ = whb; lda_ = DDIM; k0_ = (ci_ - NCHA) * 32; }      \
    _Pragma("unroll")                                                          \
    for (int j_ = 0; j_ < 6; ++j_) {                                           \
      const int s_ = j_ * 256 + t;                                             \
      wreg[j_] = *(const uint4*)(bse_ + (size_t)(s_ >> 2) * lda_ + k0_ + (s_ & 3) * 8); \
    }                                                                          \
  } while (0)

#define STOREW() do {                                                          \
    _Pragma("unroll")                                                          \
    for (int j_ = 0; j_ < 6; ++j_) {                                           \
      const int s_ = j_ * 256 + t;                                             \
      *(uint4*)(sW + (s_ >> 2) * 80 + (s_ & 3) * 16) = wreg[j_];               \
    }                                                                          \
  } while (0)

#define LOADA(A0, A1, SL) do {                                                 \
    if (av) { A0 = *(const float4*)(pA + (SL) * 32);                           \
              A1 = *(const float4*)(pA + (SL) * 32 + 4); }                     \
  } while (0)

#define STOREA(BUF, A0, A1) do {                                               \
    bf16x8 o_ = {(bf16)(A0).x, (bf16)(A0).y, (bf16)(A0).z, (bf16)(A0).w,      \
                 (bf16)(A1).x, (bf16)(A1).y, (bf16)(A1).z, (bf16)(A1).w};     \
    *(bf16x8*)(sA[BUF] + awofs) = o_;                                          \
  } while (0)

#define DOT4(A, C) ((A).x*(C).x + (A).y*(C).y + (A).z*(C).z + (A).w*(C).w)

  // ---- prologue ----
  LOADW(0);
  float4 p0 = fz, p1 = fz;
  if (av) { p0 = *(const float4*)pA; p1 = *(const float4*)(pA + 4); }
  { // classifier emb-dot, slice 0 (exact f32, R4-proven form)
    const float4 c00 = *(const float4*)(cls_w + aseg * 8);
    const float4 c01 = *(const float4*)(cls_w + aseg * 8 + 4);
    const float4 c10 = *(const float4*)(cls_w + CDIM + aseg * 8);
    const float4 c11 = *(const float4*)(cls_w + CDIM + aseg * 8 + 4);
    lp0 += DOT4(p0, c00) + DOT4(p1, c01);
    lp1 += DOT4(p0, c10) + DOT4(p1, c11);
  }
  STOREW();               // chunk 0 -> sW
  STOREA(0, p0, p1);      // slice 0 -> sA[0]
  LOADW(1);
  LOADA(aE0, aE1, 1);
  LOADA(aO0, aO1, 2);
  __syncthreads();

  // ---- one phase-A body ----
#define BODYA(C, A0, A1) do {                                                  \
    float4 cE0, cE1, cE2, cE3;                                                 \
    const bool pf_ = (C) + 1 < NCHA;                                           \
    if (pf_) { /* cls cols for slice C+1 (L3-cached) */                        \
      const int kc_ = ((C) + 1) * 32 + aseg * 8;                               \
      cE0 = *(const float4*)(cls_w + kc_);                                     \
      cE1 = *(const float4*)(cls_w + kc_ + 4);                                 \
      cE2 = *(const float4*)(cls_w + CDIM + kc_);                              \
      cE3 = *(const float4*)(cls_w + CDIM + kc_ + 4);                          \
    }                                                                          \
    const bf16x8 bR0 = *(bf16x8*)(sW + (nb      ) * 80 + lq * 16);             \
    const bf16x8 bR1 = *(bf16x8*)(sW + (nb +  16) * 80 + lq * 16);             \
    const bf16x8 bZ0 = *(bf16x8*)(sW + (nb + 128) * 80 + lq * 16);             \
    const bf16x8 bZ1 = *(bf16x8*)(sW + (nb + 144) * 80 + lq * 16);             \
    const bf16x8 bN0 = *(bf16x8*)(sW + (nb + 256) * 80 + lq * 16);             \
    const bf16x8 bN1 = *(bf16x8*)(sW + (nb + 272) * 80 + lq * 16);             \
    _Pragma("unroll")                                                          \
    for (int mt_ = 0; mt_ < 4; ++mt_) {                                        \
      const bf16x8 af_ = *(bf16x8*)(sA[(C) & 1] + (mt_ * 16 + l15) * 80 + lq * 16); \
      accR[mt_][0] = MFMA_B16(af_, bR0, accR[mt_][0]);                         \
      accR[mt_][1] = MFMA_B16(af_, bR1, accR[mt_][1]);                         \
      accZ[mt_][0] = MFMA_B16(af_, bZ0, accZ[mt_][0]);                         \
      accZ[mt_][1] = MFMA_B16(af_, bZ1, accZ[mt_][1]);                         \
      accN[mt_][0] = MFMA_B16(af_, bN0, accN[mt_][0]);                         \
      accN[mt_][1] = MFMA_B16(af_, bN1, accN[mt_][1]);                         \
    }                                                                          \
    __syncthreads();                                                           \
    STOREW();                          /* chunk C+1 (valid through 48=Wb0) */  \
    if (pf_) {                                                                 \
      STOREA(((C) + 1) & 1, A0, A1);   /* slice C+1 */                         \
      lp0 += DOT4(A0, cE0) + DOT4(A1, cE1);                                    \
      lp1 += DOT4(A0, cE2) + DOT4(A1, cE3);                                    \
    }                                                                          \
    if ((C) + 2 < NCHT) LOADW((C) + 2);                                        \
    if ((C) + 3 < NCHA) LOADA(A0, A1, (C) + 3);                                \
    __syncthreads();                                                           \
  } while (0)

  for (int c2 = 0; c2 < NCHA; c2 += 2) {
    BODYA(c2,     aE0, aE1);
    BODYA(c2 + 1, aO0, aO1);
  }
#undef BODYA

  // classifier emb-part: reduce over the 4 threads (aseg) sharing row arow
  {
    lp0 += __shfl_xor(lp0, 1); lp0 += __shfl_xor(lp0, 2);
    lp1 += __shfl_xor(lp1, 1); lp1 += __shfl_xor(lp1, 2);
    if (aseg == 0) {
      atomicAdd(&sLp[arow][0], lp0);
      atomicAdd(&sLp[arow][1], lp1);
    }
  }

  // ---- phase B transition: sW holds Wb0, wreg holds Wb1. Gather prev -> sPC.
  {
    const int prow = t >> 5;            // 0..7
    const int pc   = t & 31;            // f32 quad: col = pc*4
    float4 g[8];
#pragma unroll
    for (int p = 0; p < 8; ++p) {
      const int r = p * 8 + prow;
      g[p] = *(const float4*)(mem + (size_t)sIds[r] * DDIM + pc * 4);
    }
#pragma unroll
    for (int p = 0; p < 8; ++p) {
      const int r = p * 8 + prow;
      bf16x4 o = {(bf16)g[p].x, (bf16)g[p].y, (bf16)g[p].z, (bf16)g[p].w};
      *(bf16x4*)(sPC + r * 256 + ((pc << 3) ^ ((r & 7) << 4))) = o;
    }
  }
  __syncthreads();

  // ---- phase B bodies (4 chunks of 32 k over DDIM) ----
#define BODYB(KS) do {                                                         \
    const bf16x8 bR0 = *(bf16x8*)(sW + (nb      ) * 80 + lq * 16);             \
    const bf16x8 bR1 = *(bf16x8*)(sW + (nb +  16) * 80 + lq * 16);             \
    const bf16x8 bZ0 = *(bf16x8*)(sW + (nb + 128) * 80 + lq * 16);             \
    const bf16x8 bZ1 = *(bf16x8*)(sW + (nb + 144) * 80 + lq * 16);             \
    const bf16x8 bH0 = *(bf16x8*)(sW + (nb + 256) * 80 + lq * 16);             \
    const bf16x8 bH1 = *(bf16x8*)(sW + (nb + 272) * 80 + lq * 16);             \
    _Pragma("unroll")                                                          \
    for (int mt_ = 0; mt_ < 4; ++mt_) {                                        \
      const int m_ = mt_ * 16 + l15;                                           \
      const bf16x8 af_ = *(bf16x8*)(sPC + m_ * 256 +                           \
                          ((((KS) * 32 + lq * 8) << 1) ^ ((m_ & 7) << 4)));    \
      accR[mt_][0] = MFMA_B16(af_, bR0, accR[mt_][0]);                         \
      accR[mt_][1] = MFMA_B16(af_, bR1, accR[mt_][1]);                         \
      accZ[mt_][0] = MFMA_B16(af_, bZ0, accZ[mt_][0]);                         \
      accZ[mt_][1] = MFMA_B16(af_, bZ1, accZ[mt_][1]);                         \
      accH[mt_][0] = MFMA_B16(af_, bH0, accH[mt_][0]);                         \
      accH[mt_][1] = MFMA_B16(af_, bH1, accH[mt_][1]);                         \
    }                                                                          \
    if ((KS) < 3) {                                                            \
      __syncthreads();                                                         \
      STOREW();                                                                \
      if ((KS) + 2 < 4) LOADW(NCHA + (KS) + 2);                                \
      __syncthreads();                                                         \
    }                                                                          \
  } while (0)

  BODYB(0); BODYB(1); BODYB(2); BODYB(3);
#undef BODYB

  // ---- epilogue: gates, scatter new_mem, classifier mem-part ----
  {
    const int d0 = wn * 32 + l15;
    const float cw00 = cls_w[EDIM + d0];          // sub 0, col 0
    const float cw01 = cls_w[CDIM + EDIM + d0];   // sub 0, col 1
    const float cw10 = cls_w[EDIM + d0 + 16];     // sub 1, col 0
    const float cw11 = cls_w[CDIM + EDIM + d0 + 16];
#pragma unroll
    for (int mt = 0; mt < 4; ++mt) {
      float lpm[4][2];
#pragma unroll
      for (int j = 0; j < 4; ++j) { lpm[j][0] = 0.f; lpm[j][1] = 0.f; }
#pragma unroll
      for (int sub = 0; sub < 2; ++sub) {
        const int d = d0 + sub * 16;
        const float cw0 = sub ? cw10 : cw00;
        const float cw1 = sub ? cw11 : cw01;
#pragma unroll
        for (int j = 0; j < 4; ++j) {
          const int m = mt * 16 + lq * 4 + j;
          const float r = sigf(accR[mt][sub][j]);
          const float z = sigf(accZ[mt][sub][j]);
          const float n = tanhf_fast(accN[mt][sub][j] + r * accH[mt][sub][j]);
          const float pv = mem[(size_t)sIds[m] * DDIM + d];
          const float nv = (1.0f - z) * n + z * pv;
          if (m0 + m < Nrows) omem[(size_t)sIds[m] * DDIM + d] = nv;
          lpm[j][0] += nv * cw0;
          lpm[j][1] += nv * cw1;
        }
      }
#pragma unroll
      for (int j = 0; j < 4; ++j) {
#pragma unroll
        for (int c = 0; c < 2; ++c) {
          float v = lpm[j][c];
          v += __shfl_xor(v, 1); v += __shfl_xor(v, 2);
          v += __shfl_xor(v, 4); v += __shfl_xor(v, 8);
          if (l15 == 0) atomicAdd(&sLp[mt * 16 + lq * 4 + j][c], v);
        }
      }
    }
  }
  __syncthreads();

  if (t < 128) {
    const int m = t >> 1, c = t & 1;
    if (m0 + m < Nrows) logits[(size_t)(m0 + m) * 2 + c] = sLp[m][c];
  }
#undef LOADW
#undef STOREW
#undef LOADA
#undef STOREA
#undef DOT4
}

extern "C" void kernel_launch(void* const* d_in, const int* in_sizes, int n_in,
                              void* d_out, int out_size, void* d_ws, size_t ws_size,
                              hipStream_t stream) {
  const float* emb   = (const float*)d_in[0];
  const int*   ids   = (const int*)d_in[1];
  const float* mem   = (const float*)d_in[2];
  const float* w_ih  = (const float*)d_in[3];
  const float* w_hh  = (const float*)d_in[4];
  const float* b_ih  = (const float*)d_in[5];
  const float* b_hh  = (const float*)d_in[6];
  const float* cls_w = (const float*)d_in[7];
  const float* cls_b = (const float*)d_in[8];

  const int N    = in_sizes[0] / EDIM;   // 100000
  const int MAXN = in_sizes[2] / DDIM;   // 250000

  float* logits = (float*)d_out;
  float* omem   = (float*)d_out + (size_t)N * 2;
  bf16*  wib    = (bf16*)d_ws;
  bf16*  whb    = wib + 3 * DDIM * EDIM;

  // 1) blanket copy memory -> out (scatter overwrites active rows)
  hipMemcpyAsync(omem, mem, (size_t)MAXN * DDIM * sizeof(float),
                 hipMemcpyDeviceToDevice, stream);
  // 2) weights to bf16
  const int prep_threads = (3 * DDIM * EDIM + 3 * DDIM * DDIM) / 4;
  prep_convert<<<(prep_threads + 255) / 256, 256, 0, stream>>>(w_ih, w_hh, wib, whb);
  // 3) fused GRU + classifier
  gru_fused<<<(N + TM - 1) / TM, 256, 0, stream>>>(emb, ids, mem, b_ih, b_hh,
                                                   cls_w, cls_b, wib, whb,
                                                   logits, omem, N);
}

// Round 10
// 577.088 us; speedup vs baseline: 1.5243x; 1.5243x over previous
//
#include <hip/hip_runtime.h>
#include <hip/hip_bf16.h>

typedef __bf16 bf16;
typedef __bf16 bf16x2 __attribute__((ext_vector_type(2)));
typedef __bf16 bf16x4 __attribute__((ext_vector_type(4)));
typedef __bf16 bf16x8 __attribute__((ext_vector_type(8)));
typedef float  f32x4  __attribute__((ext_vector_type(4)));

#define EDIM 1536
#define DDIM 128
#define CDIM 1664   // E + D
#define TM   32
#define NCHA 48     // phase A chunks of 32 k

#define MFMA_B16(a, b, c) __builtin_amdgcn_mfma_f32_16x16x32_bf16((a), (b), (c), 0, 0, 0)

__device__ __forceinline__ float sigf(float x) { return 1.0f / (1.0f + __expf(-x)); }
__device__ __forceinline__ float tanhf_fast(float x) { return 2.0f / (1.0f + __expf(-2.0f * x)) - 1.0f; }

__device__ __forceinline__ void glds16(const void* g, void* l) {
  __builtin_amdgcn_global_load_lds(
      (const __attribute__((address_space(1))) unsigned int*)g,
      (__attribute__((address_space(3))) unsigned int*)l, 16, 0, 0);
}

// R4-proven linear glds staging: slot s holds row s>>2, 16B k-seg s&3.
// Quarter-wave = 4 rows x 64B contiguous (coalesced).
template <int LDA>
__device__ __forceinline__ void stageW(const bf16* __restrict__ w, int k0,
                                       char* dst, int wave, int lane) {
#pragma unroll
  for (int j = 0; j < 3; ++j) {
    const int segbase = j * 512 + wave * 64;     // wave-uniform
    const int s = segbase + lane;                // 0..1535
    const int n = s >> 2;                        // weight row 0..383
    const int q = s & 3;                         // 16B k-seg within chunk
    glds16(w + (size_t)n * LDA + k0 + q * 8, dst + (size_t)segbase * 16);
  }
}

// f32 -> bf16 weight conversion into workspace
__global__ __launch_bounds__(256) void prep_convert(const float* __restrict__ w_ih,
                                                    const float* __restrict__ w_hh,
                                                    bf16* __restrict__ wib,
                                                    bf16* __restrict__ whb) {
  const int i = (blockIdx.x * 256 + threadIdx.x) * 4;
  const int TIH = 3 * DDIM * EDIM;
  const int THH = 3 * DDIM * DDIM;
  if (i < TIH) {
    const float4 v = *(const float4*)(w_ih + i);
    bf16x4 o = {(bf16)v.x, (bf16)v.y, (bf16)v.z, (bf16)v.w};
    *(bf16x4*)(wib + i) = o;
  } else if (i < TIH + THH) {
    const int j = i - TIH;
    const float4 v = *(const float4*)(w_hh + j);
    bf16x4 o = {(bf16)v.x, (bf16)v.y, (bf16)v.z, (bf16)v.w};
    *(bf16x4*)(whb + j) = o;
  }
}

// TM=32 rows, 512 thr = 8 waves = (wn 0..3 col-group) x (ws 0..1 sub-half).
// Per-thread acc = 32 AGPR -> ~90 VGPR headroom under the 128-reg/wave wall.
// W via R4 glds dbuf; A via dist-2 register prefetch (float2/thread).
__global__ __launch_bounds__(512, 4) void gru_fused(
    const float* __restrict__ emb, const int* __restrict__ ids,
    const float* __restrict__ mem,
    const float* __restrict__ b_ih, const float* __restrict__ b_hh,
    const float* __restrict__ cls_w, const float* __restrict__ cls_b,
    const bf16* __restrict__ wib, const bf16* __restrict__ whb,
    float* __restrict__ logits, float* __restrict__ omem, int Nrows)
{
  __shared__ char  sW[2][24576];  // W chunk dbuf: 384 rows x 64B, linear (R4)
  __shared__ char  sA[2][4096];   // A slice dbuf: 32 rows x 128B (R3 swizzle)
  __shared__ char  sP[8192];      // prev gathered: 32 rows x 256B (R3 swizzle)
  __shared__ float sLp[32][2];
  __shared__ int   sIds[32];

  const int t    = threadIdx.x;
  const int lane = t & 63;
  const int wave = t >> 6;
  const int wn   = wave & 3;      // gate-col group 0..3
  const int ws   = wave >> 2;     // sub-half 0..1
  const int l15  = lane & 15;
  const int lq   = lane >> 4;     // 0..3
  const int m0   = blockIdx.x * TM;

  if (t < 32) sIds[t] = (m0 + t < Nrows) ? ids[m0 + t] : 0;
  if (t < 64) sLp[t >> 1][t & 1] = cls_b[t & 1];

  // per-thread accumulator column: nc = wn*32 + ws*16 + l15 (one col/thread)
  const int nc = wn * 32 + ws * 16 + l15;
  f32x4 accR[2], accZ[2], accN[2], accH[2];
  {
    const float br = b_ih[nc] + b_hh[nc];
    const float bz = b_ih[128 + nc] + b_hh[128 + nc];
    const float bn = b_ih[256 + nc];
    const float bh = b_hh[256 + nc];
#pragma unroll
    for (int mt = 0; mt < 2; ++mt) {
      accR[mt] = (f32x4){br, br, br, br};
      accZ[mt] = (f32x4){bz, bz, bz, bz};
      accN[mt] = (f32x4){bn, bn, bn, bn};
      accH[mt] = (f32x4){bh, bh, bh, bh};
    }
  }

  // A staging: thread t owns row arow = t>>4, f32 pair ac2 = (t&15)*2
  const int  arow = t >> 4;            // 0..31
  const int  ac2  = (t & 15) * 2;      // f32 idx within 32-k slice
  const bool av   = (m0 + arow) < Nrows;
  const float* pA = emb + (size_t)(m0 + arow) * EDIM + ac2;
  const int  awofs = arow * 128 + ((ac2 * 2) ^ ((arow & 7) << 4));
  float lp0 = 0.f, lp1 = 0.f;
  float2 aE = make_float2(0.f, 0.f), aO = aE;

#define STOREA(BUF, AR) do {                                   \
    bf16x2 o_ = {(bf16)(AR).x, (bf16)(AR).y};                  \
    *(bf16x2*)(sA[BUF] + awofs) = o_;                          \
  } while (0)

  // ---- prologue: W chunk 0, A slices 0..2 ----
  stageW<EDIM>(wib, 0, sW[0], wave, lane);
  {
    float2 p = av ? *(const float2*)pA : make_float2(0.f, 0.f);
    const float2 c0 = *(const float2*)(cls_w + ac2);
    const float2 c1 = *(const float2*)(cls_w + CDIM + ac2);
    lp0 += p.x * c0.x + p.y * c0.y;
    lp1 += p.x * c1.x + p.y * c1.y;
    STOREA(0, p);
    if (av) {
      aE = *(const float2*)(pA + 32);    // slice 1
      aO = *(const float2*)(pA + 64);    // slice 2
    }
  }
  __syncthreads();

  // ---- Phase A body: chunk C (AR holds slice C+1; reload AR with C+3) ----
#define BODYA(C, AR) do {                                                      \
    const int cur_ = (C) & 1, nxt_ = cur_ ^ 1;                                 \
    const bool pf_ = (C) + 1 < NCHA;                                           \
    if (pf_) stageW<EDIM>(wib, ((C) + 1) * 32, sW[nxt_], wave, lane);          \
    float2 c0_, c1_;                                                           \
    if (pf_) {                                                                 \
      c0_ = *(const float2*)(cls_w + ((C) + 1) * 32 + ac2);                    \
      c1_ = *(const float2*)(cls_w + CDIM + ((C) + 1) * 32 + ac2);             \
    }                                                                          \
    bf16x8 af0_ = *(bf16x8*)(sA[cur_] + (l15) * 128 +                          \
                             ((lq * 16) ^ ((l15 & 7) << 4)));                  \
    bf16x8 af1_ = *(bf16x8*)(sA[cur_] + (16 + l15) * 128 +                     \
                             ((lq * 16) ^ ((l15 & 7) << 4)));                  \
    const bf16x8 bR_ = *(bf16x8*)(sW[cur_] + (nc      ) * 64 + lq * 16);       \
    const bf16x8 bZ_ = *(bf16x8*)(sW[cur_] + (nc + 128) * 64 + lq * 16);       \
    const bf16x8 bN_ = *(bf16x8*)(sW[cur_] + (nc + 256) * 64 + lq * 16);       \
    accR[0] = MFMA_B16(af0_, bR_, accR[0]);                                    \
    accR[1] = MFMA_B16(af1_, bR_, accR[1]);                                    \
    accZ[0] = MFMA_B16(af0_, bZ_, accZ[0]);                                    \
    accZ[1] = MFMA_B16(af1_, bZ_, accZ[1]);                                    \
    accN[0] = MFMA_B16(af0_, bN_, accN[0]);                                    \
    accN[1] = MFMA_B16(af1_, bN_, accN[1]);                                    \
    if (pf_) {                                                                 \
      lp0 += (AR).x * c0_.x + (AR).y * c0_.y;                                  \
      lp1 += (AR).x * c1_.x + (AR).y * c1_.y;                                  \
      STOREA(nxt_, AR);                                                        \
    }                                                                          \
    if ((C) + 3 < NCHA && av) AR = *(const float2*)(pA + ((C) + 3) * 32);      \
    __syncthreads();                                                           \
  } while (0)

  for (int c2 = 0; c2 < NCHA; c2 += 2) {
    BODYA(c2,     aE);
    BODYA(c2 + 1, aO);
  }
#undef BODYA

  // classifier emb-part: reduce over the 16 threads sharing row arow
  {
    float v0 = lp0, v1 = lp1;
    v0 += __shfl_xor(v0, 1); v0 += __shfl_xor(v0, 2);
    v0 += __shfl_xor(v0, 4); v0 += __shfl_xor(v0, 8);
    v1 += __shfl_xor(v1, 1); v1 += __shfl_xor(v1, 2);
    v1 += __shfl_xor(v1, 4); v1 += __shfl_xor(v1, 8);
    if (l15 == 0) {
      atomicAdd(&sLp[arow][0], v0);
      atomicAdd(&sLp[arow][1], v1);
    }
  }

  // ---- Phase B: gather prev -> sP (R3 layout), gh over K=128 ----
  stageW<DDIM>(whb, 0, sW[0], wave, lane);   // last phase-A read was sW[1]
  if (t < 256) {
    const int prow = t >> 5;            // 0..7
    const int pc   = t & 31;            // f32 quad: col = pc*4
#pragma unroll
    for (int p = 0; p < 4; ++p) {
      const int r = p * 8 + prow;
      const float4 v = *(const float4*)(mem + (size_t)sIds[r] * DDIM + pc * 4);
      bf16x4 o = {(bf16)v.x, (bf16)v.y, (bf16)v.z, (bf16)v.w};
      *(bf16x4*)(sP + r * 256 + ((pc << 3) ^ ((r & 7) << 4))) = o;
    }
  }
  __syncthreads();

#pragma unroll
  for (int ks = 0; ks < 4; ++ks) {
    const int cur = ks & 1, nxt = cur ^ 1;
    if (ks + 1 < 4) stageW<DDIM>(whb, (ks + 1) * 32, sW[nxt], wave, lane);
    bf16x8 af[2];
#pragma unroll
    for (int mt = 0; mt < 2; ++mt) {
      const int m = mt * 16 + l15;
      const int kb = (ks * 32 + lq * 8) << 1;
      af[mt] = *(bf16x8*)(sP + m * 256 + (kb ^ ((m & 7) << 4)));
    }
    const bf16x8 bR = *(bf16x8*)(sW[cur] + (nc      ) * 64 + lq * 16);
    const bf16x8 bZ = *(bf16x8*)(sW[cur] + (nc + 128) * 64 + lq * 16);
    const bf16x8 bH = *(bf16x8*)(sW[cur] + (nc + 256) * 64 + lq * 16);
    accR[0] = MFMA_B16(af[0], bR, accR[0]);
    accR[1] = MFMA_B16(af[1], bR, accR[1]);
    accZ[0] = MFMA_B16(af[0], bZ, accZ[0]);
    accZ[1] = MFMA_B16(af[1], bZ, accZ[1]);
    accH[0] = MFMA_B16(af[0], bH, accH[0]);
    accH[1] = MFMA_B16(af[1], bH, accH[1]);
    __syncthreads();
  }

  // ---- Epilogue: gates, scatter new_mem, classifier mem-part ----
  {
    const int d = nc;
    const float cw0 = cls_w[EDIM + d];
    const float cw1 = cls_w[CDIM + EDIM + d];
    float lpm[8][2];
#pragma unroll
    for (int i = 0; i < 8; ++i) { lpm[i][0] = 0.f; lpm[i][1] = 0.f; }
#pragma unroll
    for (int mt = 0; mt < 2; ++mt) {
#pragma unroll
      for (int j = 0; j < 4; ++j) {
        const int m = mt * 16 + lq * 4 + j;
        const float r = sigf(accR[mt][j]);
        const float z = sigf(accZ[mt][j]);
        const float n = tanhf_fast(accN[mt][j] + r * accH[mt][j]);
        const float pv = mem[(size_t)sIds[m] * DDIM + d];
        const float nv = (1.0f - z) * n + z * pv;
        if (m0 + m < Nrows) omem[(size_t)sIds[m] * DDIM + d] = nv;
        lpm[mt * 4 + j][0] += nv * cw0;
        lpm[mt * 4 + j][1] += nv * cw1;
      }
    }
#pragma unroll
    for (int i = 0; i < 8; ++i) {
#pragma unroll
      for (int c = 0; c < 2; ++c) {
        float v = lpm[i][c];
        v += __shfl_xor(v, 1); v += __shfl_xor(v, 2);
        v += __shfl_xor(v, 4); v += __shfl_xor(v, 8);
        if (l15 == 0) {
          const int m = (i >> 2) * 16 + lq * 4 + (i & 3);
          atomicAdd(&sLp[m][c], v);
        }
      }
    }
  }
  __syncthreads();

  if (t < 64) {
    const int m = t >> 1, c = t & 1;
    if (m0 + m < Nrows) logits[(size_t)(m0 + m) * 2 + c] = sLp[m][c];
  }
#undef STOREA
}

extern "C" void kernel_launch(void* const* d_in, const int* in_sizes, int n_in,
                              void* d_out, int out_size, void* d_ws, size_t ws_size,
                              hipStream_t stream) {
  const float* emb   = (const float*)d_in[0];
  const int*   ids   = (const int*)d_in[1];
  const float* mem   = (const float*)d_in[2];
  const float* w_ih  = (const float*)d_in[3];
  const float* w_hh  = (const float*)d_in[4];
  const float* b_ih  = (const float*)d_in[5];
  const float* b_hh  = (const float*)d_in[6];
  const float* cls_w = (const float*)d_in[7];
  const float* cls_b = (const float*)d_in[8];

  const int N    = in_sizes[0] / EDIM;   // 100000
  const int MAXN = in_sizes[2] / DDIM;   // 250000

  float* logits = (float*)d_out;
  float* omem   = (float*)d_out + (size_t)N * 2;
  bf16*  wib    = (bf16*)d_ws;
  bf16*  whb    = wib + 3 * DDIM * EDIM;

  // 1) blanket copy memory -> out (scatter overwrites active rows)
  hipMemcpyAsync(omem, mem, (size_t)MAXN * DDIM * sizeof(float),
                 hipMemcpyDeviceToDevice, stream);
  // 2) weights to bf16
  const int prep_threads = (3 * DDIM * EDIM + 3 * DDIM * DDIM) / 4;
  prep_convert<<<(prep_threads + 255) / 256, 256, 0, stream>>>(w_ih, w_hh, wib, whb);
  // 3) fused GRU + classifier
  gru_fused<<<(N + TM - 1) / TM, 512, 0, stream>>>(emb, ids, mem, b_ih, b_hh,
                                                   cls_w, cls_b, wib, whb,
                                                   logits, omem, N);
}